// Round 12
// baseline (24.816 us; speedup 1.0000x reference)
//
#include <hip/hip_runtime.h>

#define NN 1000000
#define NG 20000
#define C_ 10
#define M_ 50
#define G_ 8

typedef float f32x4 __attribute__((ext_vector_type(4)));

// ---------------------------------------------------------------------------
// Single fused kernel, single-writer (no atomics, no memset). ~10 KB LDS.
// == Round-10 structure exactly; single change: plain stores in D1 (no NT) ==
// Per block of 1024 nodes:
//  A: per-wave int-width detect (ballot of 128 odd words; P_false = 50^-128)
//     | stage x/batch -> LDS | sZB/sZP log-sum-exp from global B/Pi
//     (no max-sub: |B|,|Pi| <= ~10 -> exp <= e^10, f32-safe)
//  B: lik table (stride 9) + hst argmax NIBBLE-PACKED: hpack[m] holds all 8
//     gens (4 bits each, bi<10<16) -> D1 gathers are scalar b32, no b128
//     conflicts. Packed via 8 intra-group shuffles, no scratch, no atomics.
//  C (D2 first): per-wave segment sums. Wave w owns heads in its node
//     quarter (head iff batch changes; ballot-scan). Segment end found by
//     ballot over LDS, continuing into global batch past the block edge.
//     Gather lik[x[n]] via (ns=lane>>3, r=lane&7), 3-shuffle reduce, PLAIN
//     store. Empty graphs zeroed by the uniquely-owning adjacent head.
//     Every out element written exactly once -> bit-deterministic.
//  D (D1 last): h_states: sx b32 + hpack b32 + bfe/cvt -> PLAIN coalesced
//     float4 stores (L2 write-combining path, like the 6.5 TB/s fill kernels).
// ---------------------------------------------------------------------------
__global__ __launch_bounds__(256) void k_fused(const float* __restrict__ B,
                                               const float* __restrict__ Pi,
                                               const int* __restrict__ x,
                                               const int* __restrict__ batch,
                                               float* __restrict__ out,
                                               float* __restrict__ outh) {
    __shared__ float sZB[C_ * G_];       // log sum exp over M per (c,g)
    __shared__ float sZP[G_];            // log sum exp over C per g
    __shared__ float lik[M_ * 9];        // stride 9: gcd(9,32)=1, ~2-way conflicts
    __shared__ unsigned int hpack[M_];   // 8 argmax nibbles per label
    __shared__ int sx[1024];
    __shared__ int sb[1025];             // sb[0] = batch[base-1] or -1

    const int t = threadIdx.x;
    const int lane = t & 63;
    const int w = t >> 6;
    const int base = blockIdx.x * 1024;
    const int limit = (NN - base < 1024) ? (NN - base) : 1024;  // multiple of 4

    // ---- per-wave detect: x in [0,50) -> if int64, all odd words zero
    const int vdet = x[2 * lane + 1] | x[128 + 2 * lane + 1];
    const int is64 = (__ballot(vdet != 0) == 0ULL) ? 1 : 0;

    // ---- stage x/batch -> LDS (coalesced int4)
    if (is64) {
        const int4* xq = (const int4*)x + (base >> 1);      // 2 int64 per int4
        const int4* bq = (const int4*)batch + (base >> 1);
        for (int i = t; i < (limit >> 1); i += 256) {
            const int4 a = xq[i];
            sx[2 * i] = a.x; sx[2 * i + 1] = a.z;
            const int4 b2 = bq[i];
            sb[1 + 2 * i] = b2.x; sb[2 + 2 * i] = b2.z;
        }
        if (t == 0) sb[0] = (base == 0) ? -1 : batch[2 * (base - 1)];
    } else {
        const int4* xq = (const int4*)x + (base >> 2);
        const int4* bq = (const int4*)batch + (base >> 2);
        for (int i = t; i < (limit >> 2); i += 256) {
            const int4 a = xq[i];
            sx[4 * i] = a.x; sx[4 * i + 1] = a.y; sx[4 * i + 2] = a.z; sx[4 * i + 3] = a.w;
            const int4 b2 = bq[i];
            sb[1 + 4 * i] = b2.x; sb[2 + 4 * i] = b2.y; sb[3 + 4 * i] = b2.z; sb[4 + 4 * i] = b2.w;
        }
        if (t == 0) sb[0] = (base == 0) ? -1 : batch[base - 1];
    }

    // ---- log-sum-exps from global (overlaps staging latency)
    if (t < 80) {
        const int c = t >> 3, g = t & 7;
        float Z = 0.f;
        for (int m = 0; m < M_; ++m) Z += __expf(B[(c * M_ + m) * G_ + g]);
        sZB[t] = __logf(Z);
    } else if (t < 88) {
        const int g = t - 80;
        float Z = 0.f;
        for (int c = 0; c < C_; ++c) Z += __expf(Pi[c * G_ + g]);
        sZP[g] = __logf(Z);
    }
    __syncthreads();

    // ---- tables: lik + nibble-packed argmax (B/Pi re-read, L1/L2-hot)
    for (int e = t; e < M_ * G_; e += 256) {
        const int m = e >> 3, g = e & 7;
        float s[C_];
        float bv = -1e30f;
        int bi = 0;
        for (int c = 0; c < C_; ++c) {
            const float v = (B[(c * M_ + m) * G_ + g] - sZB[c * G_ + g]) +
                            (Pi[c * G_ + g] - sZP[g]);
            s[c] = v;
            if (v > bv) { bv = v; bi = c; }  // strict > keeps FIRST max (jnp.argmax)
        }
        float Z = 0.f, W = 0.f;
        for (int c = 0; c < C_; ++c) {
            const float ee = __expf(s[c]);   // s in [-32,0]: no under/overflow
            Z += ee;
            W += ee * s[c];
        }
        lik[m * 9 + g] = W / Z;
        // pack 8 gens' argmax into one dword via aligned-8-lane-group shuffles
        // (entries of one m live in lanes (lane&~7)+0..7; all active here)
        unsigned int pk = 0;
#pragma unroll
        for (int g2 = 0; g2 < 8; ++g2)
            pk |= ((unsigned)__shfl(bi, (lane & ~7) + g2, 64) & 15u) << (4 * g2);
        if ((t & 7) == 0) hpack[m] = pk;
    }
    __syncthreads();

    // ---- D2 FIRST (latency-bound; hides under other waves' D1 stores):
    // wave w owns heads in local node range [256w, 256w+256)
    for (int rr = 0; rr < 4; ++rr) {
        const int ib = 256 * w + 64 * rr;
        const int i = ib + lane;
        const bool head = (i < limit) && (sb[1 + i] != sb[i]);
        unsigned long long hm = __ballot(head);
        while (hm) {
            const int i0 = ib + (int)__builtin_ctzll(hm);
            hm &= hm - 1;
            const int g  = sb[1 + i0];
            const int gp = sb[i0];
            if (lane < 8)                    // empty graphs in (gp, g): zero once
                for (int gg = gp + 1; gg < g; ++gg)
                    out[(size_t)gg * 8 + lane] = 0.f;

            const int n0 = base + i0;
            // find segment end: LDS locally, global batch past the block edge
            int n_end = NN;
            for (int bse = n0; ; bse += 64) {
                const int ii = bse + lane;
                int val = g + 1;             // differs (also covers ii >= NN)
                if (ii < NN)
                    val = (ii < base + limit) ? sb[1 + ii - base]
                                              : (is64 ? batch[2 * (size_t)ii] : batch[ii]);
                const unsigned long long diff = __ballot(val != g);
                if (diff) { n_end = bse + (int)__builtin_ctzll(diff); break; }
            }

            const int ns = lane >> 3, r = lane & 7;
            float acc = 0.f;
            for (int n = n0 + ns; n < n_end; n += 8) {
                const int xi = (n < base + limit) ? sx[n - base]
                                                  : (is64 ? x[2 * (size_t)n] : x[n]);
                acc += lik[xi * 9 + r];
            }
            acc += __shfl_xor(acc, 8, 64);
            acc += __shfl_xor(acc, 16, 64);
            acc += __shfl_xor(acc, 32, 64);
            if (lane < 8) out[(size_t)g * 8 + lane] = acc;

            if (n_end == NN && lane < 8)     // trailing empty graphs: zero once
                for (int gg = g + 1; gg < NG; ++gg)
                    out[(size_t)gg * 8 + lane] = 0.f;
        }
    }

    // ---- D1: h_states stream, scalar LDS + bfe/cvt + PLAIN coalesced stores
    f32x4* op = (f32x4*)outh + (size_t)base * 2;
    const int nf4 = limit * 2;
    for (int idx = t; idx < nf4; idx += 256) {
        const unsigned int pk = hpack[sx[idx >> 1]];
        const int sh = (idx & 1) * 16;
        f32x4 v;
        v.x = (float)((pk >> (sh + 0)) & 15u);
        v.y = (float)((pk >> (sh + 4)) & 15u);
        v.z = (float)((pk >> (sh + 8)) & 15u);
        v.w = (float)((pk >> (sh + 12)) & 15u);
        op[idx] = v;
    }
}

// ---------------------------------------------------------------------------
extern "C" void kernel_launch(void* const* d_in, const int* in_sizes, int n_in,
                              void* d_out, int out_size, void* d_ws, size_t ws_size,
                              hipStream_t stream) {
    const int*   x     = (const int*)d_in[0];
    const int*   batch = (const int*)d_in[1];
    const float* B     = (const float*)d_in[2];
    const float* Pi    = (const float*)d_in[3];
    float* out  = (float*)d_out;             // likelihood [NG, G_] first
    float* outh = (float*)d_out + NG * G_;   // then h_states [NN, G_]

    k_fused<<<(NN + 1023) / 1024, 256, 0, stream>>>(B, Pi, x, batch, out, outh);
}

// Round 13
// 19.619 us; speedup vs baseline: 1.2649x; 1.2649x over previous
//
#include <hip/hip_runtime.h>

#define NN 1000000
#define NG 20000
#define C_ 10
#define M_ 50
#define G_ 8

typedef float f32x4 __attribute__((ext_vector_type(4)));

// ---------------------------------------------------------------------------
// Single fused kernel, single-writer (no atomics, no memset). ~10 KB LDS.
// == Round-10 structure + NT stores; single change: 512 threads/block ==
// (8 waves/block, ~30 waves/CU -> doubles VALU/store issue concurrency;
//  D1 was issue-limited at 16 waves/CU: ~16 VALU per 16B store = 1 store
//  per ~2 cyc/CU vs the 1-per-1.5 the 6.5 TB/s write stream needs.)
// Per block of 1024 nodes:
//  A: per-wave int-width detect (ballot of 128 odd words; P_false = 50^-128)
//     | stage x/batch -> LDS | sZB/sZP log-sum-exp from global B/Pi
//     (no max-sub: |B|,|Pi| <= ~10 -> exp <= e^10, f32-safe)
//  B: lik table (stride 9) + hst argmax NIBBLE-PACKED (hpack[m], 4b/gen),
//     packed via aligned-8-lane-group shuffles.
//  C (D2 first): per-wave segment sums over its 128-node range (head iff
//     batch changes; ballot-scan; end scan continues into global batch past
//     the block edge). 3-shuffle reduce, plain store. Empty graphs zeroed by
//     the uniquely-owning adjacent head. Every out element written exactly
//     once -> bit-deterministic.
//  D (D1 last): h_states: sx b32 + hpack b32 + bfe/cvt -> NONTEMPORAL
//     coalesced float4 stores.
// ---------------------------------------------------------------------------
__global__ __launch_bounds__(512) void k_fused(const float* __restrict__ B,
                                               const float* __restrict__ Pi,
                                               const int* __restrict__ x,
                                               const int* __restrict__ batch,
                                               float* __restrict__ out,
                                               float* __restrict__ outh) {
    __shared__ float sZB[C_ * G_];       // log sum exp over M per (c,g)
    __shared__ float sZP[G_];            // log sum exp over C per g
    __shared__ float lik[M_ * 9];        // stride 9: gcd(9,32)=1, ~2-way conflicts
    __shared__ unsigned int hpack[M_];   // 8 argmax nibbles per label
    __shared__ int sx[1024];
    __shared__ int sb[1025];             // sb[0] = batch[base-1] or -1

    const int t = threadIdx.x;
    const int lane = t & 63;
    const int w = t >> 6;                // 0..7
    const int base = blockIdx.x * 1024;
    const int limit = (NN - base < 1024) ? (NN - base) : 1024;  // multiple of 4

    // ---- per-wave detect: x in [0,50) -> if int64, all odd words zero
    const int vdet = x[2 * lane + 1] | x[128 + 2 * lane + 1];
    const int is64 = (__ballot(vdet != 0) == 0ULL) ? 1 : 0;

    // ---- stage x/batch -> LDS (coalesced int4)
    if (is64) {
        const int4* xq = (const int4*)x + (base >> 1);      // 2 int64 per int4
        const int4* bq = (const int4*)batch + (base >> 1);
        for (int i = t; i < (limit >> 1); i += 512) {
            const int4 a = xq[i];
            sx[2 * i] = a.x; sx[2 * i + 1] = a.z;
            const int4 b2 = bq[i];
            sb[1 + 2 * i] = b2.x; sb[2 + 2 * i] = b2.z;
        }
        if (t == 0) sb[0] = (base == 0) ? -1 : batch[2 * (base - 1)];
    } else {
        const int4* xq = (const int4*)x + (base >> 2);
        const int4* bq = (const int4*)batch + (base >> 2);
        for (int i = t; i < (limit >> 2); i += 512) {
            const int4 a = xq[i];
            sx[4 * i] = a.x; sx[4 * i + 1] = a.y; sx[4 * i + 2] = a.z; sx[4 * i + 3] = a.w;
            const int4 b2 = bq[i];
            sb[1 + 4 * i] = b2.x; sb[2 + 4 * i] = b2.y; sb[3 + 4 * i] = b2.z; sb[4 + 4 * i] = b2.w;
        }
        if (t == 0) sb[0] = (base == 0) ? -1 : batch[base - 1];
    }

    // ---- log-sum-exps from global (overlaps staging latency)
    if (t < 80) {
        const int c = t >> 3, g = t & 7;
        float Z = 0.f;
        for (int m = 0; m < M_; ++m) Z += __expf(B[(c * M_ + m) * G_ + g]);
        sZB[t] = __logf(Z);
    } else if (t < 88) {
        const int g = t - 80;
        float Z = 0.f;
        for (int c = 0; c < C_; ++c) Z += __expf(Pi[c * G_ + g]);
        sZP[g] = __logf(Z);
    }
    __syncthreads();

    // ---- tables: lik + nibble-packed argmax (one round: t < 400)
    if (t < M_ * G_) {
        const int e = t;
        const int m = e >> 3, g = e & 7;
        float s[C_];
        float bv = -1e30f;
        int bi = 0;
        for (int c = 0; c < C_; ++c) {
            const float v = (B[(c * M_ + m) * G_ + g] - sZB[c * G_ + g]) +
                            (Pi[c * G_ + g] - sZP[g]);
            s[c] = v;
            if (v > bv) { bv = v; bi = c; }  // strict > keeps FIRST max (jnp.argmax)
        }
        float Z = 0.f, W = 0.f;
        for (int c = 0; c < C_; ++c) {
            const float ee = __expf(s[c]);   // s in [-32,0]: no under/overflow
            Z += ee;
            W += ee * s[c];
        }
        lik[m * 9 + g] = W / Z;
        // pack 8 gens' argmax into one dword via aligned-8-lane-group shuffles
        // (entries of one m live in lanes (lane&~7)+0..7; those lanes active)
        unsigned int pk = 0;
#pragma unroll
        for (int g2 = 0; g2 < 8; ++g2)
            pk |= ((unsigned)__shfl(bi, (lane & ~7) + g2, 64) & 15u) << (4 * g2);
        if ((t & 7) == 0) hpack[m] = pk;
    }
    __syncthreads();

    // ---- D2 FIRST (latency-bound; hides under other waves' D1 stores):
    // wave w owns heads in local node range [128w, 128w+128)
    for (int rr = 0; rr < 2; ++rr) {
        const int ib = 128 * w + 64 * rr;
        const int i = ib + lane;
        const bool head = (i < limit) && (sb[1 + i] != sb[i]);
        unsigned long long hm = __ballot(head);
        while (hm) {
            const int i0 = ib + (int)__builtin_ctzll(hm);
            hm &= hm - 1;
            const int g  = sb[1 + i0];
            const int gp = sb[i0];
            if (lane < 8)                    // empty graphs in (gp, g): zero once
                for (int gg = gp + 1; gg < g; ++gg)
                    out[(size_t)gg * 8 + lane] = 0.f;

            const int n0 = base + i0;
            // find segment end: LDS locally, global batch past the block edge
            int n_end = NN;
            for (int bse = n0; ; bse += 64) {
                const int ii = bse + lane;
                int val = g + 1;             // differs (also covers ii >= NN)
                if (ii < NN)
                    val = (ii < base + limit) ? sb[1 + ii - base]
                                              : (is64 ? batch[2 * (size_t)ii] : batch[ii]);
                const unsigned long long diff = __ballot(val != g);
                if (diff) { n_end = bse + (int)__builtin_ctzll(diff); break; }
            }

            const int ns = lane >> 3, r = lane & 7;
            float acc = 0.f;
            for (int n = n0 + ns; n < n_end; n += 8) {
                const int xi = (n < base + limit) ? sx[n - base]
                                                  : (is64 ? x[2 * (size_t)n] : x[n]);
                acc += lik[xi * 9 + r];
            }
            acc += __shfl_xor(acc, 8, 64);
            acc += __shfl_xor(acc, 16, 64);
            acc += __shfl_xor(acc, 32, 64);
            if (lane < 8) out[(size_t)g * 8 + lane] = acc;

            if (n_end == NN && lane < 8)     // trailing empty graphs: zero once
                for (int gg = g + 1; gg < NG; ++gg)
                    out[(size_t)gg * 8 + lane] = 0.f;
        }
    }

    // ---- D1: h_states stream, scalar LDS + bfe/cvt + NT coalesced stores
    f32x4* op = (f32x4*)outh + (size_t)base * 2;
    const int nf4 = limit * 2;
    for (int idx = t; idx < nf4; idx += 512) {
        const unsigned int pk = hpack[sx[idx >> 1]];
        const int sh = (idx & 1) * 16;
        f32x4 v;
        v.x = (float)((pk >> (sh + 0)) & 15u);
        v.y = (float)((pk >> (sh + 4)) & 15u);
        v.z = (float)((pk >> (sh + 8)) & 15u);
        v.w = (float)((pk >> (sh + 12)) & 15u);
        __builtin_nontemporal_store(v, &op[idx]);
    }
}

// ---------------------------------------------------------------------------
extern "C" void kernel_launch(void* const* d_in, const int* in_sizes, int n_in,
                              void* d_out, int out_size, void* d_ws, size_t ws_size,
                              hipStream_t stream) {
    const int*   x     = (const int*)d_in[0];
    const int*   batch = (const int*)d_in[1];
    const float* B     = (const float*)d_in[2];
    const float* Pi    = (const float*)d_in[3];
    float* out  = (float*)d_out;             // likelihood [NG, G_] first
    float* outh = (float*)d_out + NG * G_;   // then h_states [NN, G_]

    k_fused<<<(NN + 1023) / 1024, 512, 0, stream>>>(B, Pi, x, batch, out, outh);
}

// Round 14
// 19.324 us; speedup vs baseline: 1.2842x; 1.0152x over previous
//
#include <hip/hip_runtime.h>

#define NN 1000000
#define NG 20000
#define C_ 10
#define M_ 50
#define G_ 8

typedef float f32x4 __attribute__((ext_vector_type(4)));

// ---------------------------------------------------------------------------
// Single fused kernel, single-writer (no atomics, no memset). ~10 KB LDS.
// == Round-13 structure; single change: argmax table BYTE-packed (2 dwords
//    per label) so D1 unpacks via v_cvt_f32_ubyte0..3 (1 VALU/elem instead
//    of shift+and+cvt), + fully unrolled D1 (exactly 4 iters at 512 thr). ==
// Per block of 1024 nodes:
//  A: per-wave int-width detect (ballot of 128 odd words; P_false = 50^-128)
//     | stage x/batch -> LDS | sZB/sZP log-sum-exp from global B/Pi
//     (no max-sub: |B|,|Pi| <= ~10 -> exp <= e^10, f32-safe)
//  B: lik table (stride 9) + hst argmax BYTE-PACKED (hpackB[2m..2m+1]),
//     packed via aligned-8-lane-group shuffles.
//  C (D2 first): per-wave segment sums over its 128-node range (head iff
//     batch changes; ballot-scan; end scan continues into global batch past
//     the block edge). 3-shuffle reduce, plain store. Empty graphs zeroed by
//     the uniquely-owning adjacent head. Every out element written exactly
//     once -> bit-deterministic.
//  D (D1 last): h_states: sx b32 + hpackB b32 + cvt_f32_ubyte -> NONTEMPORAL
//     coalesced float4 stores.
// ---------------------------------------------------------------------------
__global__ __launch_bounds__(512) void k_fused(const float* __restrict__ B,
                                               const float* __restrict__ Pi,
                                               const int* __restrict__ x,
                                               const int* __restrict__ batch,
                                               float* __restrict__ out,
                                               float* __restrict__ outh) {
    __shared__ float sZB[C_ * G_];       // log sum exp over M per (c,g)
    __shared__ float sZP[G_];            // log sum exp over C per g
    __shared__ float lik[M_ * 9];        // stride 9: gcd(9,32)=1, ~2-way conflicts
    __shared__ unsigned int hpackB[2 * M_];  // 8 argmax bytes per label (2 dwords)
    __shared__ int sx[1024];
    __shared__ int sb[1025];             // sb[0] = batch[base-1] or -1

    const int t = threadIdx.x;
    const int lane = t & 63;
    const int w = t >> 6;                // 0..7
    const int base = blockIdx.x * 1024;
    const int limit = (NN - base < 1024) ? (NN - base) : 1024;  // multiple of 4

    // ---- per-wave detect: x in [0,50) -> if int64, all odd words zero
    const int vdet = x[2 * lane + 1] | x[128 + 2 * lane + 1];
    const int is64 = (__ballot(vdet != 0) == 0ULL) ? 1 : 0;

    // ---- stage x/batch -> LDS (coalesced int4)
    if (is64) {
        const int4* xq = (const int4*)x + (base >> 1);      // 2 int64 per int4
        const int4* bq = (const int4*)batch + (base >> 1);
        for (int i = t; i < (limit >> 1); i += 512) {
            const int4 a = xq[i];
            sx[2 * i] = a.x; sx[2 * i + 1] = a.z;
            const int4 b2 = bq[i];
            sb[1 + 2 * i] = b2.x; sb[2 + 2 * i] = b2.z;
        }
        if (t == 0) sb[0] = (base == 0) ? -1 : batch[2 * (base - 1)];
    } else {
        const int4* xq = (const int4*)x + (base >> 2);
        const int4* bq = (const int4*)batch + (base >> 2);
        for (int i = t; i < (limit >> 2); i += 512) {
            const int4 a = xq[i];
            sx[4 * i] = a.x; sx[4 * i + 1] = a.y; sx[4 * i + 2] = a.z; sx[4 * i + 3] = a.w;
            const int4 b2 = bq[i];
            sb[1 + 4 * i] = b2.x; sb[2 + 4 * i] = b2.y; sb[3 + 4 * i] = b2.z; sb[4 + 4 * i] = b2.w;
        }
        if (t == 0) sb[0] = (base == 0) ? -1 : batch[base - 1];
    }

    // ---- log-sum-exps from global (overlaps staging latency)
    if (t < 80) {
        const int c = t >> 3, g = t & 7;
        float Z = 0.f;
        for (int m = 0; m < M_; ++m) Z += __expf(B[(c * M_ + m) * G_ + g]);
        sZB[t] = __logf(Z);
    } else if (t < 88) {
        const int g = t - 80;
        float Z = 0.f;
        for (int c = 0; c < C_; ++c) Z += __expf(Pi[c * G_ + g]);
        sZP[g] = __logf(Z);
    }
    __syncthreads();

    // ---- tables: lik + byte-packed argmax (one round: t < 400)
    if (t < M_ * G_) {
        const int m = t >> 3, g = t & 7;
        float s[C_];
        float bv = -1e30f;
        int bi = 0;
        for (int c = 0; c < C_; ++c) {
            const float v = (B[(c * M_ + m) * G_ + g] - sZB[c * G_ + g]) +
                            (Pi[c * G_ + g] - sZP[g]);
            s[c] = v;
            if (v > bv) { bv = v; bi = c; }  // strict > keeps FIRST max (jnp.argmax)
        }
        float Z = 0.f, W = 0.f;
        for (int c = 0; c < C_; ++c) {
            const float ee = __expf(s[c]);   // s in [-32,0]: no under/overflow
            Z += ee;
            W += ee * s[c];
        }
        lik[m * 9 + g] = W / Z;
        // pack 8 gens' argmax into 2 dwords (1 byte each) via aligned-8-lane-
        // group shuffles (entries of one m live in lanes (lane&~7)+0..7)
        unsigned int pk0 = 0, pk1 = 0;
#pragma unroll
        for (int g2 = 0; g2 < 4; ++g2) {
            pk0 |= ((unsigned)__shfl(bi, (lane & ~7) + g2, 64) & 255u) << (8 * g2);
            pk1 |= ((unsigned)__shfl(bi, (lane & ~7) + 4 + g2, 64) & 255u) << (8 * g2);
        }
        if ((t & 7) == 0) { hpackB[2 * m] = pk0; hpackB[2 * m + 1] = pk1; }
    }
    __syncthreads();

    // ---- D2 FIRST (latency-bound; hides under other waves' D1 stores):
    // wave w owns heads in local node range [128w, 128w+128)
    for (int rr = 0; rr < 2; ++rr) {
        const int ib = 128 * w + 64 * rr;
        const int i = ib + lane;
        const bool head = (i < limit) && (sb[1 + i] != sb[i]);
        unsigned long long hm = __ballot(head);
        while (hm) {
            const int i0 = ib + (int)__builtin_ctzll(hm);
            hm &= hm - 1;
            const int g  = sb[1 + i0];
            const int gp = sb[i0];
            if (lane < 8)                    // empty graphs in (gp, g): zero once
                for (int gg = gp + 1; gg < g; ++gg)
                    out[(size_t)gg * 8 + lane] = 0.f;

            const int n0 = base + i0;
            // find segment end: LDS locally, global batch past the block edge
            int n_end = NN;
            for (int bse = n0; ; bse += 64) {
                const int ii = bse + lane;
                int val = g + 1;             // differs (also covers ii >= NN)
                if (ii < NN)
                    val = (ii < base + limit) ? sb[1 + ii - base]
                                              : (is64 ? batch[2 * (size_t)ii] : batch[ii]);
                const unsigned long long diff = __ballot(val != g);
                if (diff) { n_end = bse + (int)__builtin_ctzll(diff); break; }
            }

            const int ns = lane >> 3, r = lane & 7;
            float acc = 0.f;
            for (int n = n0 + ns; n < n_end; n += 8) {
                const int xi = (n < base + limit) ? sx[n - base]
                                                  : (is64 ? x[2 * (size_t)n] : x[n]);
                acc += lik[xi * 9 + r];
            }
            acc += __shfl_xor(acc, 8, 64);
            acc += __shfl_xor(acc, 16, 64);
            acc += __shfl_xor(acc, 32, 64);
            if (lane < 8) out[(size_t)g * 8 + lane] = acc;

            if (n_end == NN && lane < 8)     // trailing empty graphs: zero once
                for (int gg = g + 1; gg < NG; ++gg)
                    out[(size_t)gg * 8 + lane] = 0.f;
        }
    }

    // ---- D1: h_states stream — 1 LDS dword + 4 cvt_f32_ubyte + 1 NT store
    // per 16 B; fully unrolled (nf4 = limit*2, 512 threads -> <= 4 iters)
    f32x4* op = (f32x4*)outh + (size_t)base * 2;
    const int nf4 = limit * 2;
#pragma unroll
    for (int k = 0; k < 4; ++k) {
        const int idx = t + k * 512;
        if (idx < nf4) {
            const unsigned int pk = hpackB[2 * sx[idx >> 1] + (idx & 1)];
            f32x4 v;
            v.x = (float)(pk & 0xffu);           // v_cvt_f32_ubyte0
            v.y = (float)((pk >> 8) & 0xffu);    // v_cvt_f32_ubyte1
            v.z = (float)((pk >> 16) & 0xffu);   // v_cvt_f32_ubyte2
            v.w = (float)(pk >> 24);             // v_cvt_f32_ubyte3
            __builtin_nontemporal_store(v, &op[idx]);
        }
    }
}

// ---------------------------------------------------------------------------
extern "C" void kernel_launch(void* const* d_in, const int* in_sizes, int n_in,
                              void* d_out, int out_size, void* d_ws, size_t ws_size,
                              hipStream_t stream) {
    const int*   x     = (const int*)d_in[0];
    const int*   batch = (const int*)d_in[1];
    const float* B     = (const float*)d_in[2];
    const float* Pi    = (const float*)d_in[3];
    float* out  = (float*)d_out;             // likelihood [NG, G_] first
    float* outh = (float*)d_out + NG * G_;   // then h_states [NN, G_]

    k_fused<<<(NN + 1023) / 1024, 512, 0, stream>>>(B, Pi, x, batch, out, outh);
}